// Round 1
// baseline (1229.029 us; speedup 1.0000x reference)
//
#include <hip/hip_runtime.h>
#include <stdint.h>

#pragma clang fp contract(off)

#define BATCH 65536
#define INDIM 1024
#define MDIM  64

// ---------------- JAX threefry2x32 (partitionable mode) ----------------
struct K2 { uint32_t a, b; };

__device__ __forceinline__ void tf_round(uint32_t &x0, uint32_t &x1, int r) {
  x0 += x1;
  x1 = (x1 << r) | (x1 >> (32 - r));
  x1 ^= x0;
}

__device__ __forceinline__ K2 tf(K2 k, uint32_t c0, uint32_t c1) {
  uint32_t ks0 = k.a, ks1 = k.b, ks2 = k.a ^ k.b ^ 0x1BD11BDAu;
  uint32_t x0 = c0 + ks0, x1 = c1 + ks1;
  tf_round(x0,x1,13); tf_round(x0,x1,15); tf_round(x0,x1,26); tf_round(x0,x1,6);
  x0 += ks1; x1 += ks2 + 1u;
  tf_round(x0,x1,17); tf_round(x0,x1,29); tf_round(x0,x1,16); tf_round(x0,x1,24);
  x0 += ks2; x1 += ks0 + 2u;
  tf_round(x0,x1,13); tf_round(x0,x1,15); tf_round(x0,x1,26); tf_round(x0,x1,6);
  x0 += ks0; x1 += ks1 + 3u;
  tf_round(x0,x1,17); tf_round(x0,x1,29); tf_round(x0,x1,16); tf_round(x0,x1,24);
  x0 += ks1; x1 += ks2 + 4u;
  tf_round(x0,x1,13); tf_round(x0,x1,15); tf_round(x0,x1,26); tf_round(x0,x1,6);
  x0 += ks2; x1 += ks0 + 5u;
  K2 o; o.a = x0; o.b = x1; return o;
}

// partitionable 32-bit random bits for flat element idx: xor-fold of the two words
__device__ __forceinline__ uint32_t rbits32(K2 k, uint32_t idx) {
  K2 r = tf(k, 0u, idx);
  return r.a ^ r.b;
}

__device__ __forceinline__ float u01f(uint32_t bits) {
  return __uint_as_float((bits >> 9) | 0x3f800000u) - 1.0f;
}

// ---------------- XLA-matching transcendentals ----------------
__device__ __forceinline__ float xla_log(float x) { return (float)log((double)x); }
__device__ __forceinline__ float xla_exp(float x) { return (float)exp((double)x); }

__device__ __forceinline__ float xla_log1p(float x) {
  float ax = fabsf(x);
  if (ax < 1e-4f) {
    float t = (-0.5f * x) + 1.0f;
    return t * x;
  }
  return xla_log(x + 1.0f);   // f32 add first, exactly like XLA EmitLog1p
}

__device__ __forceinline__ float xla_erfinv(float x) {
  float w = -xla_log1p((-x) * x);
  float p;
  if (w < 5.0f) {
    w = w - 2.5f;
    p = 2.81022636e-08f;
    p = 3.43273939e-07f + p * w;
    p = -3.5233877e-06f + p * w;
    p = -4.39150654e-06f + p * w;
    p = 0.00021858087f + p * w;
    p = -0.00125372503f + p * w;
    p = -0.00417768164f + p * w;
    p = 0.246640727f + p * w;
    p = 1.50140941f + p * w;
  } else {
    w = sqrtf(w) - 3.0f;
    p = -0.000200214257f;
    p = 0.000100950558f + p * w;
    p = 0.00134934322f + p * w;
    p = -0.00367342844f + p * w;
    p = 0.00573950773f + p * w;
    p = -0.0076224613f + p * w;
    p = 0.00943887047f + p * w;
    p = 1.00167406f + p * w;
    p = 2.83297682f + p * w;
  }
  return p * x;
}

// jax.random.normal(key, ()) for f32
__device__ __forceinline__ float jr_normal(K2 key) {
  float u01 = u01f(rbits32(key, 0u));
  float uu = u01 * 2.0f + (-0.99999994f);   // (hi-lo)=2.0f exactly; lo=-(1-2^-24)
  uu = fmaxf(-0.99999994f, uu);
  return 1.41421356f * xla_erfinv(uu);      // f32(sqrt(2)) * erfinv
}

// jax _gamma_one(key, alpha=31.5, log_space=True) -- Marsaglia-Tsang
__device__ __forceinline__ float gamma315_log(K2 ekey) {
  const float d = 31.5f - 0.33333334f;
  const float c = 0.33333334f / sqrtf(d);
  K2 key = tf(ekey, 0u, 0u);   // boost split: child0 = new key (child1 unused, alpha>=1)
  float X = 0.0f, V = 1.0f, U = 2.0f;
  while (true) {
    float x4 = (X * X) * (X * X);
    float sq = 1.0f - 0.0331f * x4;
    bool cont = false;
    if (U >= sq) {
      float lv  = xla_log(V);
      float rhs = X * 0.5f + d * ((1.0f - V) + lv);
      cont = (xla_log(U) >= rhs);
    }
    if (!cont) break;
    K2 kn = tf(key, 0u, 0u);   // split3 -> (key, x_key, U_key)
    K2 kx = tf(key, 0u, 1u);
    K2 kU = tf(key, 0u, 2u);
    key = kn;
    float xn, vv;
    K2 xkey = kx;
    do {                        // inner while v<=0 (split2: child1 is subkey)
      K2 sub = tf(xkey, 0u, 1u);
      xkey = tf(xkey, 0u, 0u);
      xn = jr_normal(sub);
      vv = 1.0f + xn * c;
    } while (vv <= 0.0f);
    X = xn * xn;
    V = (vv * vv) * vv;
    U = u01f(rbits32(kU, 0u));  // uniform(U_key, ())
  }
  return xla_log(d) + xla_log(V);
}

// jax.random.beta(ke, 31.5, 31.5) element i (loggamma-based)
__device__ __forceinline__ float beta315(K2 ka, K2 kb, uint32_t i) {
  float lga = gamma315_log(tf(ka, 0u, i));
  float lgb = gamma315_log(tf(kb, 0u, i));
  float lm = fmaxf(lga, lgb);
  float ea = xla_exp(lga - lm);
  float eb = xla_exp(lgb - lm);
  return ea / (ea + eb);
}

// ---------------- kernel 1: f32 GEMM + row-normalize + softplus kappa ----------------
__launch_bounds__(256)
__global__ void gemm_norm_kernel(const float* __restrict__ x,
                                 const float* __restrict__ Wm,
                                 const float* __restrict__ bm,
                                 const float* __restrict__ Wk,
                                 const float* __restrict__ bk,
                                 float* __restrict__ miu_out,
                                 float* __restrict__ kap_out) {
  __shared__ float xs[64 * 65];     // [row][kk], +1 pad -> conflict-free
  __shared__ float ssp[4][64];
  const int t = threadIdx.x;
  const int lane = t & 63;
  const int w = t >> 6;
  const int cw = __builtin_amdgcn_readfirstlane(w) * 16;  // wave-uniform col base -> s_loads for W
  const long row0 = (long)blockIdx.x * 64;

  float acc[16];
#pragma unroll
  for (int j = 0; j < 16; ++j) acc[j] = 0.0f;
  float acck = 0.0f;

  for (int k0 = 0; k0 < INDIM; k0 += 64) {
#pragma unroll
    for (int l = 0; l < 4; ++l) {
      int idx = t + 256 * l;
      int r = idx >> 4;
      int q = idx & 15;
      const float4 vv = *(const float4*)(x + (row0 + r) * INDIM + k0 + 4 * q);
      xs[r * 65 + 4 * q + 0] = vv.x;
      xs[r * 65 + 4 * q + 1] = vv.y;
      xs[r * 65 + 4 * q + 2] = vv.z;
      xs[r * 65 + 4 * q + 3] = vv.w;
    }
    __syncthreads();
#pragma unroll
    for (int kk = 0; kk < 64; ++kk) {
      float aval = xs[lane * 65 + kk];
      const float* wr = Wm + (long)(k0 + kk) * MDIM + cw;
#pragma unroll
      for (int j = 0; j < 16; ++j) acc[j] = fmaf(aval, wr[j], acc[j]);
      if (w == 0) acck = fmaf(aval, Wk[k0 + kk], acck);
    }
    __syncthreads();
  }

  float ss = 0.0f;
#pragma unroll
  for (int j = 0; j < 16; ++j) { acc[j] = acc[j] + bm[cw + j]; ss += acc[j] * acc[j]; }
  ssp[w][lane] = ss;
  __syncthreads();
  float tot = ssp[0][lane] + ssp[1][lane] + ssp[2][lane] + ssp[3][lane];
  float nrm = sqrtf(tot);
#pragma unroll
  for (int j = 0; j < 16; ++j) acc[j] = acc[j] / nrm;

  if (w == 0) {
    float y = acck + bk[0];
    // jax.nn.softplus = logaddexp(y,0) = max(y,0) + log1p(exp(-|y|))
    float sp = fmaxf(y, 0.0f) + xla_log1p(xla_exp(-fabsf(y)));
    kap_out[row0 + lane] = sp + 1.0f;
  }

  __syncthreads();
#pragma unroll
  for (int j = 0; j < 16; ++j) xs[lane * 65 + cw + j] = acc[j];
  __syncthreads();
#pragma unroll
  for (int l = 0; l < 4; ++l) {
    int idx = t + 256 * l;
    int r = idx >> 4;
    int q = idx & 15;
    float4 o;
    o.x = xs[r * 65 + 4 * q + 0];
    o.y = xs[r * 65 + 4 * q + 1];
    o.z = xs[r * 65 + 4 * q + 2];
    o.w = xs[r * 65 + 4 * q + 3];
    *(float4*)(miu_out + (row0 + r) * MDIM + 4 * q) = o;
  }
}

// ---------------- kernel 2: vMF rejection sample + Householder ----------------
__launch_bounds__(256)
__global__ void vmf_sample_kernel(float* __restrict__ z,   // in: normalized miu, out: z
                                  const float* __restrict__ kap) {
  __shared__ float vlds[63 * 256];
  const int tl = threadIdx.x;
  const int b = blockIdx.x * 256 + tl;

  // key(42) -> split 3 -> (ke, ku, kv); beta: split(ke) -> (key_a, key_b)
  K2 root; root.a = 0u; root.b = 42u;
  const K2 ke  = tf(root, 0u, 0u);
  const K2 ku  = tf(root, 0u, 1u);
  const K2 kv  = tf(root, 0u, 2u);
  const K2 kga = tf(ke, 0u, 0u);
  const K2 kgb = tf(ke, 0u, 1u);

  const float kappa = kap[b];
  const float s2 = kappa * kappa;
  const float cenv = sqrtf(4.0f * s2 + 3969.0f);
  const float b_true = (-2.0f * kappa + cenv) / 63.0f;
  const float b_app = 63.0f / (4.0f * kappa);
  const float sclip = fminf(fmaxf(kappa - 10.0f, 0.0f), 1.0f);
  const float bb = b_app * sclip + b_true * (1.0f - sclip);
  const float aenv = (63.0f + 2.0f * kappa + cenv) / 4.0f;
  const float denv = (4.0f * aenv) * bb / (1.0f + bb) - 261.01748776266656f; // f32(63*ln63 in f64)

  // first-accept walk (== argmax over pre-drawn K proposals; idx=0 if none accept)
  float w_sel = 0.0f, w_first = 0.0f;
  bool found = false;
#pragma unroll 1
  for (uint32_t k = 0; k < 64u && !found; ++k) {
    uint32_t i = k * 65536u + (uint32_t)b;
    float e = beta315(kga, kgb, i);
    float u01 = u01f(rbits32(ku, i));
    float uu = fmaxf(1e-7f, u01 * (1.0f - 1e-7f) + 1e-7f);
    float den = 1.0f - (1.0f - bb) * e;
    float wk = (1.0f - (1.0f + bb) * e) / den;
    float tt = (2.0f * aenv) * bb / den;
    float lhs = 63.0f * xla_log(tt) - tt + denv;
    if (k == 0u) w_first = wk;
    if (lhs > xla_log(uu)) { w_sel = wk; found = true; }
  }
  if (!found) w_sel = w_first;

  // tangent direction: 63 normals, normalize
  float ssum = 0.0f;
#pragma unroll 1
  for (int j = 0; j < 63; ++j) {
    uint32_t fi = (uint32_t)b * 63u + (uint32_t)j;
    float u01 = u01f(rbits32(kv, fi));
    float uu = u01 * 2.0f + (-0.99999994f);
    uu = fmaxf(-0.99999994f, uu);
    float xn = 1.41421356f * xla_erfinv(uu);
    vlds[j * 256 + tl] = xn;
    ssum += xn * xn;
  }
  float vn = sqrtf(ssum);

  float wperp = sqrtf(fmaxf(1.0f - w_sel * w_sel, 1e-10f));
#pragma unroll 1
  for (int j = 0; j < 63; ++j) {
    float vj = vlds[j * 256 + tl] / vn;     // v / ||v||
    vlds[j * 256 + tl] = wperp * vj;        // x_dir[1+j]
  }

  // Householder: uh = (e1 - miu)/(||e1-miu|| + 1e-5); z = x_dir - 2*(x_dir.uh)*uh
  const long base = (long)b * 64;
  float uss = 0.0f;
#pragma unroll 1
  for (int j = 0; j < 64; ++j) {
    float mu = z[base + j];
    float uh = (j == 0 ? 1.0f : 0.0f) - mu;
    uss += uh * uh;
  }
  float unorm = sqrtf(uss) + 1e-5f;

  float dot = 0.0f;
#pragma unroll 1
  for (int j = 0; j < 64; ++j) {
    float mu = z[base + j];
    float uh = ((j == 0 ? 1.0f : 0.0f) - mu) / unorm;
    float xd = (j == 0) ? w_sel : vlds[(j - 1) * 256 + tl];
    dot += xd * uh;
  }
  float sc = 2.0f * dot;
#pragma unroll 1
  for (int j = 0; j < 64; ++j) {
    float mu = z[base + j];
    float uh = ((j == 0 ? 1.0f : 0.0f) - mu) / unorm;
    float xd = (j == 0) ? w_sel : vlds[(j - 1) * 256 + tl];
    z[base + j] = xd - sc * uh;
  }
}

extern "C" void kernel_launch(void* const* d_in, const int* in_sizes, int n_in,
                              void* d_out, int out_size, void* d_ws, size_t ws_size,
                              hipStream_t stream) {
  const float* x  = (const float*)d_in[0];
  const float* Wm = (const float*)d_in[1];
  const float* bm = (const float*)d_in[2];
  const float* Wk = (const float*)d_in[3];
  const float* bk = (const float*)d_in[4];
  float* out = (float*)d_out;
  float* kap = (float*)d_ws;   // 65536 f32 = 256 KB scratch

  hipLaunchKernelGGL(gemm_norm_kernel, dim3(BATCH / 64), dim3(256), 0, stream,
                     x, Wm, bm, Wk, bk, out, kap);
  hipLaunchKernelGGL(vmf_sample_kernel, dim3(BATCH / 256), dim3(256), 0, stream,
                     out, kap);
}

// Round 2
// 629.952 us; speedup vs baseline: 1.9510x; 1.9510x over previous
//
#include <hip/hip_runtime.h>
#include <stdint.h>

#pragma clang fp contract(off)

#define BATCH 65536
#define INDIM 1024
#define MDIM  64
#define GROWS 128
#define GBK   32
#define XS    129   // padded dword stride for transposed x tile

// ---------------- JAX threefry2x32 (partitionable mode) ----------------
struct K2 { uint32_t a, b; };

__device__ __forceinline__ void tf_round(uint32_t &x0, uint32_t &x1, int r) {
  x0 += x1;
  x1 = (x1 << r) | (x1 >> (32 - r));
  x1 ^= x0;
}

__device__ __forceinline__ K2 tf(K2 k, uint32_t c0, uint32_t c1) {
  uint32_t ks0 = k.a, ks1 = k.b, ks2 = k.a ^ k.b ^ 0x1BD11BDAu;
  uint32_t x0 = c0 + ks0, x1 = c1 + ks1;
  tf_round(x0,x1,13); tf_round(x0,x1,15); tf_round(x0,x1,26); tf_round(x0,x1,6);
  x0 += ks1; x1 += ks2 + 1u;
  tf_round(x0,x1,17); tf_round(x0,x1,29); tf_round(x0,x1,16); tf_round(x0,x1,24);
  x0 += ks2; x1 += ks0 + 2u;
  tf_round(x0,x1,13); tf_round(x0,x1,15); tf_round(x0,x1,26); tf_round(x0,x1,6);
  x0 += ks0; x1 += ks1 + 3u;
  tf_round(x0,x1,17); tf_round(x0,x1,29); tf_round(x0,x1,16); tf_round(x0,x1,24);
  x0 += ks1; x1 += ks2 + 4u;
  tf_round(x0,x1,13); tf_round(x0,x1,15); tf_round(x0,x1,26); tf_round(x0,x1,6);
  x0 += ks2; x1 += ks0 + 5u;
  K2 o; o.a = x0; o.b = x1; return o;
}

__device__ __forceinline__ uint32_t rbits32(K2 k, uint32_t idx) {
  K2 r = tf(k, 0u, idx);
  return r.a ^ r.b;
}

__device__ __forceinline__ float u01f(uint32_t bits) {
  return __uint_as_float((bits >> 9) | 0x3f800000u) - 1.0f;
}

// ---------------- XLA-matching transcendentals ----------------
__device__ __forceinline__ float xla_log(float x) { return (float)log((double)x); }
__device__ __forceinline__ float xla_exp(float x) { return (float)exp((double)x); }

__device__ __forceinline__ float xla_log1p(float x) {
  float ax = fabsf(x);
  if (ax < 1e-4f) {
    float t = (-0.5f * x) + 1.0f;
    return t * x;
  }
  return xla_log(x + 1.0f);   // f32 add first, exactly like XLA EmitLog1p
}

__device__ __forceinline__ float xla_erfinv(float x) {
  float w = -xla_log1p((-x) * x);
  float p;
  if (w < 5.0f) {
    w = w - 2.5f;
    p = 2.81022636e-08f;
    p = 3.43273939e-07f + p * w;
    p = -3.5233877e-06f + p * w;
    p = -4.39150654e-06f + p * w;
    p = 0.00021858087f + p * w;
    p = -0.00125372503f + p * w;
    p = -0.00417768164f + p * w;
    p = 0.246640727f + p * w;
    p = 1.50140941f + p * w;
  } else {
    w = sqrtf(w) - 3.0f;
    p = -0.000200214257f;
    p = 0.000100950558f + p * w;
    p = 0.00134934322f + p * w;
    p = -0.00367342844f + p * w;
    p = 0.00573950773f + p * w;
    p = -0.0076224613f + p * w;
    p = 0.00943887047f + p * w;
    p = 1.00167406f + p * w;
    p = 2.83297682f + p * w;
  }
  return p * x;
}

__device__ __forceinline__ float jr_normal(K2 key) {
  float u01 = u01f(rbits32(key, 0u));
  float uu = u01 * 2.0f + (-0.99999994f);
  uu = fmaxf(-0.99999994f, uu);
  return 1.41421356f * xla_erfinv(uu);
}

// jax _gamma_one(key, alpha=31.5, log_space=True) -- Marsaglia-Tsang
__device__ __forceinline__ float gamma315_log(K2 ekey) {
  const float d = 31.5f - 0.33333334f;
  const float c = 0.33333334f / sqrtf(d);
  K2 key = tf(ekey, 0u, 0u);
  float X = 0.0f, V = 1.0f, U = 2.0f;
  while (true) {
    float x4 = (X * X) * (X * X);
    float sq = 1.0f - 0.0331f * x4;
    bool cont = false;
    if (U >= sq) {
      float lv  = xla_log(V);
      float rhs = X * 0.5f + d * ((1.0f - V) + lv);
      cont = (xla_log(U) >= rhs);
    }
    if (!cont) break;
    K2 kn = tf(key, 0u, 0u);
    K2 kx = tf(key, 0u, 1u);
    K2 kU = tf(key, 0u, 2u);
    key = kn;
    float xn, vv;
    K2 xkey = kx;
    do {
      K2 sub = tf(xkey, 0u, 1u);
      xkey = tf(xkey, 0u, 0u);
      xn = jr_normal(sub);
      vv = 1.0f + xn * c;
    } while (vv <= 0.0f);
    X = xn * xn;
    V = (vv * vv) * vv;
    U = u01f(rbits32(kU, 0u));
  }
  return xla_log(d) + xla_log(V);
}

__device__ __forceinline__ float beta315(K2 ka, K2 kb, uint32_t i) {
  float lga = gamma315_log(tf(ka, 0u, i));
  float lgb = gamma315_log(tf(kb, 0u, i));
  float lm = fmaxf(lga, lgb);
  float ea = xla_exp(lga - lm);
  float eb = xla_exp(lgb - lm);
  return ea / (ea + eb);
}

// ---------------- kernel 1: f32 GEMM + row-normalize + softplus kappa ----------------
__launch_bounds__(256)
__global__ void gemm_norm_kernel(const float* __restrict__ x,
                                 const float* __restrict__ Wm,
                                 const float* __restrict__ bm,
                                 const float* __restrict__ Wk,
                                 const float* __restrict__ bk,
                                 float* __restrict__ miu_out,
                                 float* __restrict__ kap_out) {
  __shared__ float xsT[GBK * XS];     // transposed x tile [kk][row], pad-129
  __shared__ float ssq[4][GROWS];
  const int t = threadIdx.x;
  const int l = t & 63;
  const int w = t >> 6;
  const int cw = __builtin_amdgcn_readfirstlane(w) * 16;  // wave-uniform -> s_loads for W
  const long row0 = (long)blockIdx.x * GROWS;

  float acc0[16], acc1[16];
#pragma unroll
  for (int c = 0; c < 16; ++c) { acc0[c] = 0.0f; acc1[c] = 0.0f; }
  float acck0 = 0.0f, acck1 = 0.0f;

  const int rs = t >> 3;   // staging row base (0..31), rows rs+32*lam
  const int qs = t & 7;    // staging k-quad
  float4 st[4];

#define LOADT(K0)                                                              \
  {                                                                            \
    _Pragma("unroll")                                                          \
    for (int lam = 0; lam < 4; ++lam) {                                        \
      int r = rs + 32 * lam;                                                   \
      st[lam] = *(const float4*)(x + (row0 + r) * (long)INDIM + (K0) + 4 * qs);\
    }                                                                          \
  }

  LOADT(0);
  for (int ks = 0; ks < INDIM / GBK; ++ks) {
    __syncthreads();
    // transposed store, stride 129 -> <=2-way bank aliasing (free)
#pragma unroll
    for (int lam = 0; lam < 4; ++lam) {
      int r = rs + 32 * lam;
      int kb = 4 * qs;
      xsT[(kb + 0) * XS + r] = st[lam].x;
      xsT[(kb + 1) * XS + r] = st[lam].y;
      xsT[(kb + 2) * XS + r] = st[lam].z;
      xsT[(kb + 3) * XS + r] = st[lam].w;
    }
    __syncthreads();
    if (ks + 1 < INDIM / GBK) LOADT((ks + 1) * GBK);

    const float* wbase = Wm + (long)ks * GBK * MDIM + cw;
    if (w == 3) {
#pragma unroll
      for (int kk = 0; kk < GBK; ++kk) {
        float a0 = xsT[kk * XS + l];
        float a1 = xsT[kk * XS + l + 64];
        const float* wr = wbase + (long)kk * MDIM;
        float4 w0 = *(const float4*)(wr);
        float4 w1 = *(const float4*)(wr + 4);
        float4 w2 = *(const float4*)(wr + 8);
        float4 w3 = *(const float4*)(wr + 12);
        const float wv[16] = {w0.x,w0.y,w0.z,w0.w, w1.x,w1.y,w1.z,w1.w,
                              w2.x,w2.y,w2.z,w2.w, w3.x,w3.y,w3.z,w3.w};
#pragma unroll
        for (int c = 0; c < 16; ++c) {
          acc0[c] = fmaf(a0, wv[c], acc0[c]);
          acc1[c] = fmaf(a1, wv[c], acc1[c]);
        }
        float swk = Wk[ks * GBK + kk];
        acck0 = fmaf(a0, swk, acck0);
        acck1 = fmaf(a1, swk, acck1);
      }
    } else {
#pragma unroll
      for (int kk = 0; kk < GBK; ++kk) {
        float a0 = xsT[kk * XS + l];
        float a1 = xsT[kk * XS + l + 64];
        const float* wr = wbase + (long)kk * MDIM;
        float4 w0 = *(const float4*)(wr);
        float4 w1 = *(const float4*)(wr + 4);
        float4 w2 = *(const float4*)(wr + 8);
        float4 w3 = *(const float4*)(wr + 12);
        const float wv[16] = {w0.x,w0.y,w0.z,w0.w, w1.x,w1.y,w1.z,w1.w,
                              w2.x,w2.y,w2.z,w2.w, w3.x,w3.y,w3.z,w3.w};
#pragma unroll
        for (int c = 0; c < 16; ++c) {
          acc0[c] = fmaf(a0, wv[c], acc0[c]);
          acc1[c] = fmaf(a1, wv[c], acc1[c]);
        }
      }
    }
  }

  // bias + per-wave sum of squares (same per-row chain order as v1)
  const float* bmp = bm + cw;
  float4 b0 = *(const float4*)(bmp);
  float4 b1 = *(const float4*)(bmp + 4);
  float4 b2 = *(const float4*)(bmp + 8);
  float4 b3 = *(const float4*)(bmp + 12);
  const float bv[16] = {b0.x,b0.y,b0.z,b0.w, b1.x,b1.y,b1.z,b1.w,
                        b2.x,b2.y,b2.z,b2.w, b3.x,b3.y,b3.z,b3.w};
  float ss0 = 0.0f, ss1 = 0.0f;
#pragma unroll
  for (int c = 0; c < 16; ++c) {
    acc0[c] = acc0[c] + bv[c]; ss0 += acc0[c] * acc0[c];
    acc1[c] = acc1[c] + bv[c]; ss1 += acc1[c] * acc1[c];
  }
  ssq[w][l] = ss0;
  ssq[w][l + 64] = ss1;
  __syncthreads();
  float tot0 = ssq[0][l] + ssq[1][l] + ssq[2][l] + ssq[3][l];
  float tot1 = ssq[0][l + 64] + ssq[1][l + 64] + ssq[2][l + 64] + ssq[3][l + 64];
  float nrm0 = sqrtf(tot0);
  float nrm1 = sqrtf(tot1);
#pragma unroll
  for (int c = 0; c < 16; ++c) { acc0[c] = acc0[c] / nrm0; acc1[c] = acc1[c] / nrm1; }

  float* o0 = miu_out + (row0 + l) * 64 + cw;
  float* o1 = miu_out + (row0 + l + 64) * 64 + cw;
  *(float4*)(o0 + 0)  = make_float4(acc0[0],  acc0[1],  acc0[2],  acc0[3]);
  *(float4*)(o0 + 4)  = make_float4(acc0[4],  acc0[5],  acc0[6],  acc0[7]);
  *(float4*)(o0 + 8)  = make_float4(acc0[8],  acc0[9],  acc0[10], acc0[11]);
  *(float4*)(o0 + 12) = make_float4(acc0[12], acc0[13], acc0[14], acc0[15]);
  *(float4*)(o1 + 0)  = make_float4(acc1[0],  acc1[1],  acc1[2],  acc1[3]);
  *(float4*)(o1 + 4)  = make_float4(acc1[4],  acc1[5],  acc1[6],  acc1[7]);
  *(float4*)(o1 + 8)  = make_float4(acc1[8],  acc1[9],  acc1[10], acc1[11]);
  *(float4*)(o1 + 12) = make_float4(acc1[12], acc1[13], acc1[14], acc1[15]);

  if (w == 3) {
    float y0 = acck0 + bk[0];
    float y1 = acck1 + bk[0];
    float sp0 = fmaxf(y0, 0.0f) + xla_log1p(xla_exp(-fabsf(y0)));
    float sp1 = fmaxf(y1, 0.0f) + xla_log1p(xla_exp(-fabsf(y1)));
    kap_out[row0 + l] = sp0 + 1.0f;
    kap_out[row0 + l + 64] = sp1 + 1.0f;
  }
#undef LOADT
}

// ---------------- kernel 2: vMF rejection sample + Householder ----------------
__launch_bounds__(64)
__global__ void vmf_sample_kernel(float* __restrict__ z,   // in: normalized miu, out: z
                                  const float* __restrict__ kap) {
  __shared__ float vlds[63 * 65];   // raw tangent normals, stride-65 (odd -> conflict-free transpose read)
  __shared__ float wsel_lds[64];
  __shared__ float scale_lds[64];
  const int tl = threadIdx.x;                  // 0..63
  const int b = blockIdx.x * 64 + tl;

  K2 root; root.a = 0u; root.b = 42u;
  const K2 ke  = tf(root, 0u, 0u);
  const K2 ku  = tf(root, 0u, 1u);
  const K2 kv  = tf(root, 0u, 2u);
  const K2 kga = tf(ke, 0u, 0u);
  const K2 kgb = tf(ke, 0u, 1u);

  const float kappa = kap[b];
  const float s2 = kappa * kappa;
  const float cenv = sqrtf(4.0f * s2 + 3969.0f);
  const float b_true = (-2.0f * kappa + cenv) / 63.0f;
  const float b_app = 63.0f / (4.0f * kappa);
  const float sclip = fminf(fmaxf(kappa - 10.0f, 0.0f), 1.0f);
  const float bb = b_app * sclip + b_true * (1.0f - sclip);
  const float aenv = (63.0f + 2.0f * kappa + cenv) / 4.0f;
  const float denv = (4.0f * aenv) * bb / (1.0f + bb) - 261.01748776266656f;

  // first-accept walk (identical numerics to passing v1)
  float w_sel = 0.0f, w_first = 0.0f;
  bool found = false;
#pragma unroll 1
  for (uint32_t k = 0; k < 64u && !found; ++k) {
    uint32_t i = k * 65536u + (uint32_t)b;
    float e = beta315(kga, kgb, i);
    float u01 = u01f(rbits32(ku, i));
    float uu = fmaxf(1e-7f, u01 * (1.0f - 1e-7f) + 1e-7f);
    float den = 1.0f - (1.0f - bb) * e;
    float wk = (1.0f - (1.0f + bb) * e) / den;
    float tt = (2.0f * aenv) * bb / den;
    float lhs = 63.0f * xla_log(tt) - tt + denv;
    if (k == 0u) w_first = wk;
    if (lhs > xla_log(uu)) { w_sel = wk; found = true; }
  }
  if (!found) w_sel = w_first;

  // tangent normals: store raw, serial ssum (order preserved)
  float ssum = 0.0f;
#pragma unroll 3
  for (int j = 0; j < 63; ++j) {
    uint32_t fi = (uint32_t)b * 63u + (uint32_t)j;
    float u01 = u01f(rbits32(kv, fi));
    float uu = u01 * 2.0f + (-0.99999994f);
    uu = fmaxf(-0.99999994f, uu);
    float xn = 1.41421356f * xla_erfinv(uu);
    vlds[j * 65 + tl] = xn;
    ssum += xn * xn;
  }
  float vn = sqrtf(ssum);
  float wperp = sqrtf(fmaxf(1.0f - w_sel * w_sel, 1e-10f));
  wsel_lds[tl] = w_sel;
  scale_lds[tl] = wperp / vn;
  __syncthreads();

  // Householder, wave-per-row transposed: lane = output column j (coalesced)
  const long rowbase = (long)blockIdx.x * 64;
#pragma unroll 1
  for (int r = 0; r < 64; ++r) {
    float mu = z[(rowbase + r) * 64 + tl];
    float uh = (tl == 0 ? 1.0f : 0.0f) - mu;
    int jj = (tl == 0) ? 0 : (tl - 1);
    float xd = (tl == 0) ? wsel_lds[r] : vlds[jj * 65 + r] * scale_lds[r];
    float s1 = uh * uh;
    float sd = xd * uh;
#pragma unroll
    for (int o = 32; o > 0; o >>= 1) {
      s1 += __shfl_xor(s1, o);
      sd += __shfl_xor(sd, o);
    }
    float unorm = sqrtf(s1) + 1e-5f;
    float sc = 2.0f * (sd / unorm);
    z[(rowbase + r) * 64 + tl] = xd - sc * (uh / unorm);
  }
}

extern "C" void kernel_launch(void* const* d_in, const int* in_sizes, int n_in,
                              void* d_out, int out_size, void* d_ws, size_t ws_size,
                              hipStream_t stream) {
  const float* x  = (const float*)d_in[0];
  const float* Wm = (const float*)d_in[1];
  const float* bm = (const float*)d_in[2];
  const float* Wk = (const float*)d_in[3];
  const float* bk = (const float*)d_in[4];
  float* out = (float*)d_out;
  float* kap = (float*)d_ws;   // 65536 f32 = 256 KB scratch

  hipLaunchKernelGGL(gemm_norm_kernel, dim3(BATCH / GROWS), dim3(256), 0, stream,
                     x, Wm, bm, Wk, bk, out, kap);
  hipLaunchKernelGGL(vmf_sample_kernel, dim3(BATCH / 64), dim3(64), 0, stream,
                     out, kap);
}

// Round 3
// 514.684 us; speedup vs baseline: 2.3879x; 1.2240x over previous
//
#include <hip/hip_runtime.h>
#include <stdint.h>

#pragma clang fp contract(off)

#define BATCH 65536
#define INDIM 1024
#define MDIM  64
#define GROWS 128
#define GBK   32
#define XS    129   // padded dword stride for transposed x tile

// ---------------- JAX threefry2x32 (partitionable mode) ----------------
struct K2 { uint32_t a, b; };

__device__ __forceinline__ void tf_round(uint32_t &x0, uint32_t &x1, int r) {
  x0 += x1;
  x1 = (x1 << r) | (x1 >> (32 - r));
  x1 ^= x0;
}

__device__ __forceinline__ K2 tf(K2 k, uint32_t c0, uint32_t c1) {
  uint32_t ks0 = k.a, ks1 = k.b, ks2 = k.a ^ k.b ^ 0x1BD11BDAu;
  uint32_t x0 = c0 + ks0, x1 = c1 + ks1;
  tf_round(x0,x1,13); tf_round(x0,x1,15); tf_round(x0,x1,26); tf_round(x0,x1,6);
  x0 += ks1; x1 += ks2 + 1u;
  tf_round(x0,x1,17); tf_round(x0,x1,29); tf_round(x0,x1,16); tf_round(x0,x1,24);
  x0 += ks2; x1 += ks0 + 2u;
  tf_round(x0,x1,13); tf_round(x0,x1,15); tf_round(x0,x1,26); tf_round(x0,x1,6);
  x0 += ks0; x1 += ks1 + 3u;
  tf_round(x0,x1,17); tf_round(x0,x1,29); tf_round(x0,x1,16); tf_round(x0,x1,24);
  x0 += ks1; x1 += ks2 + 4u;
  tf_round(x0,x1,13); tf_round(x0,x1,15); tf_round(x0,x1,26); tf_round(x0,x1,6);
  x0 += ks2; x1 += ks0 + 5u;
  K2 o; o.a = x0; o.b = x1; return o;
}

__device__ __forceinline__ uint32_t rbits32(K2 k, uint32_t idx) {
  K2 r = tf(k, 0u, idx);
  return r.a ^ r.b;
}

__device__ __forceinline__ float u01f(uint32_t bits) {
  return __uint_as_float((bits >> 9) | 0x3f800000u) - 1.0f;
}

// ---------------- XLA-matching transcendentals ----------------
__device__ __forceinline__ float xla_log(float x) { return (float)log((double)x); }
__device__ __forceinline__ float xla_exp(float x) { return (float)exp((double)x); }

__device__ __forceinline__ float xla_log1p(float x) {
  float ax = fabsf(x);
  if (ax < 1e-4f) {
    float t = (-0.5f * x) + 1.0f;
    return t * x;
  }
  return xla_log(x + 1.0f);   // f32 add first, exactly like XLA EmitLog1p
}

__device__ __forceinline__ float xla_erfinv(float x) {
  float w = -xla_log1p((-x) * x);
  float p;
  if (w < 5.0f) {
    w = w - 2.5f;
    p = 2.81022636e-08f;
    p = 3.43273939e-07f + p * w;
    p = -3.5233877e-06f + p * w;
    p = -4.39150654e-06f + p * w;
    p = 0.00021858087f + p * w;
    p = -0.00125372503f + p * w;
    p = -0.00417768164f + p * w;
    p = 0.246640727f + p * w;
    p = 1.50140941f + p * w;
  } else {
    w = sqrtf(w) - 3.0f;
    p = -0.000200214257f;
    p = 0.000100950558f + p * w;
    p = 0.00134934322f + p * w;
    p = -0.00367342844f + p * w;
    p = 0.00573950773f + p * w;
    p = -0.0076224613f + p * w;
    p = 0.00943887047f + p * w;
    p = 1.00167406f + p * w;
    p = 2.83297682f + p * w;
  }
  return p * x;
}

__device__ __forceinline__ float jr_normal(K2 key) {
  float u01 = u01f(rbits32(key, 0u));
  float uu = u01 * 2.0f + (-0.99999994f);
  uu = fmaxf(-0.99999994f, uu);
  return 1.41421356f * xla_erfinv(uu);
}

// jax _gamma_one(key, alpha=31.5, log_space=True) -- Marsaglia-Tsang
__device__ __forceinline__ float gamma315_log(K2 ekey) {
  const float d = 31.5f - 0.33333334f;
  const float c = 0.33333334f / sqrtf(d);
  K2 key = tf(ekey, 0u, 0u);
  float X = 0.0f, V = 1.0f, U = 2.0f;
  while (true) {
    float x4 = (X * X) * (X * X);
    float sq = 1.0f - 0.0331f * x4;
    bool cont = false;
    if (U >= sq) {
      float lv  = xla_log(V);
      float rhs = X * 0.5f + d * ((1.0f - V) + lv);
      cont = (xla_log(U) >= rhs);
    }
    if (!cont) break;
    K2 kn = tf(key, 0u, 0u);
    K2 kx = tf(key, 0u, 1u);
    K2 kU = tf(key, 0u, 2u);
    key = kn;
    float xn, vv;
    K2 xkey = kx;
    do {
      K2 sub = tf(xkey, 0u, 1u);
      xkey = tf(xkey, 0u, 0u);
      xn = jr_normal(sub);
      vv = 1.0f + xn * c;
    } while (vv <= 0.0f);
    X = xn * xn;
    V = (vv * vv) * vv;
    U = u01f(rbits32(kU, 0u));
  }
  return xla_log(d) + xla_log(V);
}

__device__ __forceinline__ float beta315(K2 ka, K2 kb, uint32_t i) {
  float lga = gamma315_log(tf(ka, 0u, i));
  float lgb = gamma315_log(tf(kb, 0u, i));
  float lm = fmaxf(lga, lgb);
  float ea = xla_exp(lga - lm);
  float eb = xla_exp(lgb - lm);
  return ea / (ea + eb);
}

// ---------------- kernel 1: f32 GEMM (x,W in LDS) + row-normalize + softplus kappa ----------------
__launch_bounds__(256)
__global__ void gemm_norm_kernel(const float* __restrict__ x,
                                 const float* __restrict__ Wm,
                                 const float* __restrict__ bm,
                                 const float* __restrict__ Wk,
                                 const float* __restrict__ bk,
                                 float* __restrict__ miu_out,
                                 float* __restrict__ kap_out) {
  __shared__ float xsT[GBK * XS];        // transposed x tile [kk][row], pad-129
  __shared__ float wlds[GBK * MDIM];     // W tile [kk][col] linear
  __shared__ float wklds[GBK];           // Wk tile
  __shared__ float ssq[4][GROWS];
  const int t = threadIdx.x;
  const int l = t & 63;
  const int w = t >> 6;
  const int cw = __builtin_amdgcn_readfirstlane(w) * 16;  // wave-uniform col base
  const long row0 = (long)blockIdx.x * GROWS;

  float acc0[16], acc1[16];
#pragma unroll
  for (int c = 0; c < 16; ++c) { acc0[c] = 0.0f; acc1[c] = 0.0f; }
  float acck0 = 0.0f, acck1 = 0.0f;

  const int rs = t >> 3;   // staging row base (0..31), rows rs+32*lam
  const int qs = t & 7;    // staging k-quad
  float4 st[4];
  float4 ws0, ws1;
  float wks;

#define LOADT(K0)                                                              \
  {                                                                            \
    _Pragma("unroll")                                                          \
    for (int lam = 0; lam < 4; ++lam) {                                        \
      int r = rs + 32 * lam;                                                   \
      st[lam] = *(const float4*)(x + (row0 + r) * (long)INDIM + (K0) + 4 * qs);\
    }                                                                          \
  }
#define LOADW(KS)                                                              \
  {                                                                            \
    const float* wp = Wm + (long)(KS) * GBK * MDIM + t * 8;                    \
    ws0 = *(const float4*)(wp);                                                \
    ws1 = *(const float4*)(wp + 4);                                            \
    if (t < GBK) wks = Wk[(KS) * GBK + t];                                     \
  }

  LOADT(0);
  LOADW(0);
  for (int ks = 0; ks < INDIM / GBK; ++ks) {
    __syncthreads();
    // transposed x store, stride 129 -> <=2-way bank aliasing (free)
#pragma unroll
    for (int lam = 0; lam < 4; ++lam) {
      int r = rs + 32 * lam;
      int kb = 4 * qs;
      xsT[(kb + 0) * XS + r] = st[lam].x;
      xsT[(kb + 1) * XS + r] = st[lam].y;
      xsT[(kb + 2) * XS + r] = st[lam].z;
      xsT[(kb + 3) * XS + r] = st[lam].w;
    }
    // W tile store (linear, canonical b128 pattern)
    *(float4*)(&wlds[t * 8])     = ws0;
    *(float4*)(&wlds[t * 8 + 4]) = ws1;
    if (t < GBK) wklds[t] = wks;
    __syncthreads();
    if (ks + 1 < INDIM / GBK) { LOADT((ks + 1) * GBK); LOADW(ks + 1); }

    if (w == 3) {
#pragma unroll
      for (int kk = 0; kk < GBK; ++kk) {
        float a0 = xsT[kk * XS + l];
        float a1 = xsT[kk * XS + l + 64];
        const float* wr = &wlds[kk * MDIM + cw];   // uniform addr -> ds_read_b128 broadcast
        float4 w0 = *(const float4*)(wr);
        float4 w1 = *(const float4*)(wr + 4);
        float4 w2 = *(const float4*)(wr + 8);
        float4 w3 = *(const float4*)(wr + 12);
        const float wv[16] = {w0.x,w0.y,w0.z,w0.w, w1.x,w1.y,w1.z,w1.w,
                              w2.x,w2.y,w2.z,w2.w, w3.x,w3.y,w3.z,w3.w};
#pragma unroll
        for (int c = 0; c < 16; ++c) {
          acc0[c] = fmaf(a0, wv[c], acc0[c]);
          acc1[c] = fmaf(a1, wv[c], acc1[c]);
        }
        float swk = wklds[kk];
        acck0 = fmaf(a0, swk, acck0);
        acck1 = fmaf(a1, swk, acck1);
      }
    } else {
#pragma unroll
      for (int kk = 0; kk < GBK; ++kk) {
        float a0 = xsT[kk * XS + l];
        float a1 = xsT[kk * XS + l + 64];
        const float* wr = &wlds[kk * MDIM + cw];
        float4 w0 = *(const float4*)(wr);
        float4 w1 = *(const float4*)(wr + 4);
        float4 w2 = *(const float4*)(wr + 8);
        float4 w3 = *(const float4*)(wr + 12);
        const float wv[16] = {w0.x,w0.y,w0.z,w0.w, w1.x,w1.y,w1.z,w1.w,
                              w2.x,w2.y,w2.z,w2.w, w3.x,w3.y,w3.z,w3.w};
#pragma unroll
        for (int c = 0; c < 16; ++c) {
          acc0[c] = fmaf(a0, wv[c], acc0[c]);
          acc1[c] = fmaf(a1, wv[c], acc1[c]);
        }
      }
    }
  }

  // bias + per-wave sum of squares (same per-row chain order)
  const float* bmp = bm + cw;
  float4 b0 = *(const float4*)(bmp);
  float4 b1 = *(const float4*)(bmp + 4);
  float4 b2 = *(const float4*)(bmp + 8);
  float4 b3 = *(const float4*)(bmp + 12);
  const float bv[16] = {b0.x,b0.y,b0.z,b0.w, b1.x,b1.y,b1.z,b1.w,
                        b2.x,b2.y,b2.z,b2.w, b3.x,b3.y,b3.z,b3.w};
  float ss0 = 0.0f, ss1 = 0.0f;
#pragma unroll
  for (int c = 0; c < 16; ++c) {
    acc0[c] = acc0[c] + bv[c]; ss0 += acc0[c] * acc0[c];
    acc1[c] = acc1[c] + bv[c]; ss1 += acc1[c] * acc1[c];
  }
  ssq[w][l] = ss0;
  ssq[w][l + 64] = ss1;
  __syncthreads();
  float tot0 = ssq[0][l] + ssq[1][l] + ssq[2][l] + ssq[3][l];
  float tot1 = ssq[0][l + 64] + ssq[1][l + 64] + ssq[2][l + 64] + ssq[3][l + 64];
  float nrm0 = sqrtf(tot0);
  float nrm1 = sqrtf(tot1);
#pragma unroll
  for (int c = 0; c < 16; ++c) { acc0[c] = acc0[c] / nrm0; acc1[c] = acc1[c] / nrm1; }

  float* o0 = miu_out + (row0 + l) * 64 + cw;
  float* o1 = miu_out + (row0 + l + 64) * 64 + cw;
  *(float4*)(o0 + 0)  = make_float4(acc0[0],  acc0[1],  acc0[2],  acc0[3]);
  *(float4*)(o0 + 4)  = make_float4(acc0[4],  acc0[5],  acc0[6],  acc0[7]);
  *(float4*)(o0 + 8)  = make_float4(acc0[8],  acc0[9],  acc0[10], acc0[11]);
  *(float4*)(o0 + 12) = make_float4(acc0[12], acc0[13], acc0[14], acc0[15]);
  *(float4*)(o1 + 0)  = make_float4(acc1[0],  acc1[1],  acc1[2],  acc1[3]);
  *(float4*)(o1 + 4)  = make_float4(acc1[4],  acc1[5],  acc1[6],  acc1[7]);
  *(float4*)(o1 + 8)  = make_float4(acc1[8],  acc1[9],  acc1[10], acc1[11]);
  *(float4*)(o1 + 12) = make_float4(acc1[12], acc1[13], acc1[14], acc1[15]);

  if (w == 3) {
    float y0 = acck0 + bk[0];
    float y1 = acck1 + bk[0];
    float sp0 = fmaxf(y0, 0.0f) + xla_log1p(xla_exp(-fabsf(y0)));
    float sp1 = fmaxf(y1, 0.0f) + xla_log1p(xla_exp(-fabsf(y1)));
    kap_out[row0 + l] = sp0 + 1.0f;
    kap_out[row0 + l + 64] = sp1 + 1.0f;
  }
#undef LOADT
#undef LOADW
}

// ---------------- kernel 2: vMF sample, 4 lanes/row accept walk + wave-per-row Householder ----------------
__launch_bounds__(256)
__global__ void vmf_sample_kernel(float* __restrict__ z,   // in: normalized miu, out: z
                                  const float* __restrict__ kap) {
  const int t = threadIdx.x;
  const int lane = t & 63;
  const int q = t & 3;                       // lane within quad
  const int rowblk = t >> 2;                 // row within block, 0..63
  const int gb = blockIdx.x * 64 + rowblk;   // global row for phase A

  K2 root; root.a = 0u; root.b = 42u;
  const K2 ke  = tf(root, 0u, 0u);
  const K2 ku  = tf(root, 0u, 1u);
  const K2 kv  = tf(root, 0u, 2u);
  const K2 kga = tf(ke, 0u, 0u);
  const K2 kgb = tf(ke, 0u, 1u);

  // ---- phase A: speculative first-accept walk, 4 proposals per round ----
  const float kappa = kap[gb];
  const float s2 = kappa * kappa;
  const float cenv = sqrtf(4.0f * s2 + 3969.0f);
  const float b_true = (-2.0f * kappa + cenv) / 63.0f;
  const float b_app = 63.0f / (4.0f * kappa);
  const float sclip = fminf(fmaxf(kappa - 10.0f, 0.0f), 1.0f);
  const float bb = b_app * sclip + b_true * (1.0f - sclip);
  const float aenv = (63.0f + 2.0f * kappa + cenv) / 4.0f;
  const float denv = (4.0f * aenv) * bb / (1.0f + bb) - 261.01748776266656f;

  float w_sel = 0.0f, w_first = 0.0f;
  bool found = false;
#pragma unroll 1
  for (int round = 0; round < 16; ++round) {
    if (!__any(!found)) break;
    bool acc = false; float wk = 0.0f;
    if (!found) {
      uint32_t k = (uint32_t)(round * 4 + q);
      uint32_t i = k * 65536u + (uint32_t)gb;
      float e = beta315(kga, kgb, i);            // bit-identical per-k chain
      float u01 = u01f(rbits32(ku, i));
      float uu = fmaxf(1e-7f, u01 * (1.0f - 1e-7f) + 1e-7f);
      float den = 1.0f - (1.0f - bb) * e;
      wk = (1.0f - (1.0f + bb) * e) / den;
      float tt2 = (2.0f * aenv) * bb / den;
      float lhs = 63.0f * xla_log(tt2) - tt2 + denv;
      acc = lhs > xla_log(uu);
      if (round == 0 && q == 0) w_first = wk;
    }
    unsigned long long bal = __ballot(acc);
    unsigned nib = (unsigned)((bal >> ((lane >> 2) << 2)) & 0xFull);
    int winner = nib ? (__ffs(nib) - 1) : 0;
    float wcand = __shfl(wk, (lane & 60) + winner);   // all lanes active here
    if (!found && nib) { w_sel = wcand; found = true; }
  }
  float wf = __shfl(w_first, lane & 60);
  if (!found) w_sel = wf;                      // no accept in K=64 -> argmax==0

  // ---- phase B: wave-per-row tangent + Householder (rows owned by same wave) ----
  const int wv = t >> 6;
#pragma unroll 1
  for (int rr = 0; rr < 16; ++rr) {
    const int rib = wv * 16 + rr;                        // row in block
    const long gr = (long)blockIdx.x * 64 + rib;         // global row
    float wsel_r = __shfl(w_sel, rr * 4);                // quad q0 lane = 4*rr

    // tangent normal j=lane (bit-identical element values; reduction order smooth)
    float xn = 0.0f;
    if (lane < 63) {
      uint32_t fi = (uint32_t)gr * 63u + (uint32_t)lane;
      float u01 = u01f(rbits32(kv, fi));
      float uu = u01 * 2.0f + (-0.99999994f);
      uu = fmaxf(-0.99999994f, uu);
      xn = 1.41421356f * xla_erfinv(uu);
    }
    float ss = xn * xn;
#pragma unroll
    for (int o = 32; o > 0; o >>= 1) ss += __shfl_xor(ss, o);
    float vn = sqrtf(ss);
    float wperp = sqrtf(fmaxf(1.0f - wsel_r * wsel_r, 1e-10f));

    float xs_ = __shfl_up(xn, 1);
    float xd = (lane == 0) ? wsel_r : wperp * (xs_ / vn);

    float mu = z[gr * 64 + lane];
    float uh = ((lane == 0) ? 1.0f : 0.0f) - mu;
    float uss = uh * uh;
#pragma unroll
    for (int o = 32; o > 0; o >>= 1) uss += __shfl_xor(uss, o);
    float unorm = sqrtf(uss) + 1e-5f;
    float uhn = uh / unorm;

    float dd = xd * uhn;
#pragma unroll
    for (int o = 32; o > 0; o >>= 1) dd += __shfl_xor(dd, o);

    z[gr * 64 + lane] = xd - 2.0f * dd * uhn;
  }
}

extern "C" void kernel_launch(void* const* d_in, const int* in_sizes, int n_in,
                              void* d_out, int out_size, void* d_ws, size_t ws_size,
                              hipStream_t stream) {
  const float* x  = (const float*)d_in[0];
  const float* Wm = (const float*)d_in[1];
  const float* bm = (const float*)d_in[2];
  const float* Wk = (const float*)d_in[3];
  const float* bk = (const float*)d_in[4];
  float* out = (float*)d_out;
  float* kap = (float*)d_ws;   // 65536 f32 = 256 KB scratch

  hipLaunchKernelGGL(gemm_norm_kernel, dim3(BATCH / GROWS), dim3(256), 0, stream,
                     x, Wm, bm, Wk, bk, out, kap);
  hipLaunchKernelGGL(vmf_sample_kernel, dim3(BATCH / 64), dim3(256), 0, stream,
                     out, kap);
}